// Round 1
// baseline (281.800 us; speedup 1.0000x reference)
//
#include <hip/hip_runtime.h>
#include <hip/hip_bf16.h>
#include <stdint.h>

// B=2, S=2048, E=1024, H=16, D=64.
// Outputs concatenated in d_out (fp32): out [2,2048,1024] then probs [2,16,2048,2048].
// Workspace layout (bf16/short elems): Xb | Wt(q,k,v,o transposed) | Q | K | V | ctx
//   each 4,194,304 shorts -> 48 MB total.

typedef __attribute__((ext_vector_type(8))) short bf16x8;
typedef __attribute__((ext_vector_type(4))) short bf16x4v;
typedef __attribute__((ext_vector_type(4))) float f32x4;

#define DEV static __device__ __forceinline__

DEV short f2bs(float f) {
  union { __hip_bfloat16 b; short s; } u;
  u.b = __float2bfloat16(f);
  return u.s;
}
DEV float bs2f(short s) {
  union { unsigned int u; float f; } x;
  x.u = ((unsigned int)(unsigned short)s) << 16;
  return x.f;
}
DEV f32x4 mfma16(bf16x8 a, bf16x8 b, f32x4 c) {
  return __builtin_amdgcn_mfma_f32_16x16x32_bf16(a, b, c, 0, 0, 0);
}
typedef const __attribute__((address_space(1))) void* gas1_t;
typedef __attribute__((address_space(3))) void* las3_t;
DEV void gload_lds16(const void* g, void* l) {
  // LDS dest is wave-uniform base + lane*16 (guide §5); callers pass per-wave base.
  __builtin_amdgcn_global_load_lds((gas1_t)(uintptr_t)g, (las3_t)(uint32_t)(uintptr_t)l,
                                   16, 0, 0);
}

// ---------- fp32 -> bf16 convert of hidden_states ----------
__global__ void cvt_x_kernel(const float* __restrict__ X, short* __restrict__ Xb) {
  size_t i = (size_t)blockIdx.x * blockDim.x + threadIdx.x;  // 8 elems each
  const float4* X4 = (const float4*)X;
  float4 a = X4[2 * i], c = X4[2 * i + 1];
  bf16x8 o;
  o[0] = f2bs(a.x); o[1] = f2bs(a.y); o[2] = f2bs(a.z); o[3] = f2bs(a.w);
  o[4] = f2bs(c.x); o[5] = f2bs(c.y); o[6] = f2bs(c.z); o[7] = f2bs(c.w);
  *(bf16x8*)(Xb + i * 8) = o;
}

// ---------- W [k][n] fp32 -> Wt [mat][n][k] bf16 (tiled transpose) ----------
__global__ void cvt_wt_kernel(const float* __restrict__ Wq, const float* __restrict__ Wk,
                              const float* __restrict__ Wv, const float* __restrict__ Wo,
                              short* __restrict__ Wt) {
  __shared__ short tile[64][68];
  int mat = blockIdx.y;
  const float* W = mat == 0 ? Wq : mat == 1 ? Wk : mat == 2 ? Wv : Wo;
  int kb = (blockIdx.x >> 4) * 64, nb = (blockIdx.x & 15) * 64;
  int t = threadIdx.x;
#pragma unroll
  for (int it = 0; it < 4; ++it) {
    int idx = it * 256 + t;
    int row = idx >> 4, c4 = (idx & 15) * 4;
    float4 v = *(const float4*)(W + (size_t)(kb + row) * 1024 + nb + c4);
    tile[row][c4 + 0] = f2bs(v.x); tile[row][c4 + 1] = f2bs(v.y);
    tile[row][c4 + 2] = f2bs(v.z); tile[row][c4 + 3] = f2bs(v.w);
  }
  __syncthreads();
#pragma unroll
  for (int it = 0; it < 4; ++it) {
    int idx = it * 256 + t;
    int rn = idx >> 4, c4 = (idx & 15) * 4;
    bf16x4v o;
    o[0] = tile[c4 + 0][rn]; o[1] = tile[c4 + 1][rn];
    o[2] = tile[c4 + 2][rn]; o[3] = tile[c4 + 3][rn];
    *(bf16x4v*)(Wt + (((size_t)mat) << 20) + (size_t)(nb + rn) * 1024 + kb + c4) = o;
  }
}

// ---------- m97-structure GEMM: A[M][1024] bf16 @ Bt[N][1024] bf16 ----------
// MODE 0: QKV projection -> Q (scaled 1/8), K, V in [B,H,S,D] bf16.
// MODE 1: out projection -> fp32 out [4096][1024] (+bias).
template <int MODE>
__global__ __launch_bounds__(256, 2)
void gemm_bt_kernel(const short* __restrict__ A, const short* __restrict__ Bt,
                    const float* __restrict__ bias0, const float* __restrict__ bias1,
                    const float* __restrict__ bias2,
                    short* __restrict__ o0, short* __restrict__ o1, short* __restrict__ o2,
                    float* __restrict__ fout) {
  __shared__ short As[128 * 32];
  __shared__ short Bs[128 * 32];
  const int m0 = blockIdx.x * 128, n0 = blockIdx.y * 128;
  const int t = threadIdx.x, w = t >> 6, l = t & 63, g = l >> 4, r = l & 15;
  const int wr = (w >> 1) * 64, wc = (w & 1) * 64;
  f32x4 acc[4][4] = {};
  for (int k0 = 0; k0 < 1024; k0 += 32) {
    gload_lds16(A + (size_t)(m0 + (t >> 2)) * 1024 + k0 + (t & 3) * 8, As + w * 512);
    gload_lds16(A + (size_t)(m0 + 64 + (t >> 2)) * 1024 + k0 + (t & 3) * 8, As + 2048 + w * 512);
    gload_lds16(Bt + (size_t)(n0 + (t >> 2)) * 1024 + k0 + (t & 3) * 8, Bs + w * 512);
    gload_lds16(Bt + (size_t)(n0 + 64 + (t >> 2)) * 1024 + k0 + (t & 3) * 8, Bs + 2048 + w * 512);
    __syncthreads();
    bf16x8 af[4], bfv[4];
#pragma unroll
    for (int i = 0; i < 4; i++) af[i] = *(const bf16x8*)(As + (wr + i * 16 + r) * 32 + g * 8);
#pragma unroll
    for (int j = 0; j < 4; j++) bfv[j] = *(const bf16x8*)(Bs + (wc + j * 16 + r) * 32 + g * 8);
#pragma unroll
    for (int i = 0; i < 4; i++)
#pragma unroll
      for (int j = 0; j < 4; j++) acc[i][j] = mfma16(af[i], bfv[j], acc[i][j]);
    __syncthreads();
  }
  if constexpr (MODE == 0) {
#pragma unroll
    for (int j = 0; j < 4; j++) {
      int ng = n0 + wc + j * 16 + r;
      int mat = ng >> 10, nn = ng & 1023, hh = nn >> 6, dd = nn & 63;
      const float* bp = mat == 0 ? bias0 : (mat == 1 ? bias1 : bias2);
      short* dst = mat == 0 ? o0 : (mat == 1 ? o1 : o2);
      float bv = bp[nn];
      float sc = (mat == 0) ? 0.125f : 1.0f;  // fold 1/sqrt(D) into Q
#pragma unroll
      for (int i = 0; i < 4; i++) {
#pragma unroll
        for (int q = 0; q < 4; q++) {
          int m = m0 + wr + i * 16 + g * 4 + q;
          int bb = m >> 11, ss = m & 2047;
          dst[((size_t)(bb * 16 + hh) * 2048 + ss) * 64 + dd] = f2bs((acc[i][j][q] + bv) * sc);
        }
      }
    }
  } else {
#pragma unroll
    for (int i = 0; i < 4; i++)
#pragma unroll
      for (int q = 0; q < 4; q++) {
        int m = m0 + wr + i * 16 + g * 4 + q;
#pragma unroll
        for (int j = 0; j < 4; j++) {
          int ng = n0 + wc + j * 16 + r;
          fout[(size_t)m * 1024 + ng] = acc[i][j][q] + bias0[ng];
        }
      }
  }
}

// ---------- fused attention: two-pass flash + exact probs output ----------
// Block: one (b,h) x 128 q-rows; 4 waves x 32 q-rows. K-tiles of 128.
// Pass A: row max m + row sum l (swapped QK^T: mfma(K, Q) so a q-row's scores
// live in 4 lanes -> 2 shfl_xor reduce). Pass B: recompute S, P=exp(s-m),
// pack bf16 to per-wave LDS, PV MFMA + coalesced probs write (x 1/l).
__global__ __launch_bounds__(256, 2)
void attn_kernel(const short* __restrict__ Qm, const short* __restrict__ Km,
                 const short* __restrict__ Vm, float* __restrict__ probs,
                 short* __restrict__ ctx) {
  __shared__ short SQV[128 * 72];     // Q tile early; V^T tile (64 x 136) in pass B
  __shared__ short Ks[128 * 72];      // padded stride 72 shorts: bank-safe
  __shared__ short Ps[4][32 * 136];   // per-wave P tile [32 q][128 k], stride 136
  __shared__ float rls[128];          // 1/l per q-row
  short* Qs = SQV;
  short* Vt = SQV;
  const int bh = blockIdx.y, q0 = blockIdx.x * 128;
  const int bb = bh >> 4, hh = bh & 15;
  const short* Qp = Qm + (size_t)bh * 2048 * 64;
  const short* Kp = Km + (size_t)bh * 2048 * 64;
  const short* Vp = Vm + (size_t)bh * 2048 * 64;
  float* Pp = probs + (size_t)bh * 2048 * 2048;
  const int t = threadIdx.x, w = t >> 6, l = t & 63, g = l >> 4, r = l & 15;

  // stage Q tile (reg-staged, padded)
#pragma unroll
  for (int it = 0; it < 4; ++it) {
    int idx = it * 256 + t;
    bf16x8 v = *(const bf16x8*)(Qp + (size_t)(q0 + (idx >> 3)) * 64 + (idx & 7) * 8);
    *(bf16x8*)(Qs + (idx >> 3) * 72 + (idx & 7) * 8) = v;
  }
  __syncthreads();
  // hoist Q fragments (B-operand: col=q, 8 consecutive d) — Qs dead afterwards
  bf16x8 qf[2][2];
#pragma unroll
  for (int qj = 0; qj < 2; qj++)
#pragma unroll
    for (int df = 0; df < 2; df++)
      qf[qj][df] = *(const bf16x8*)(Qs + (w * 32 + qj * 16 + r) * 72 + df * 32 + g * 8);
  __syncthreads();

  float mrow[2] = {-1e30f, -1e30f};
  float lrow[2] = {0.f, 0.f};

  // -------- pass A: row stats --------
  for (int kt = 0; kt < 16; ++kt) {
#pragma unroll
    for (int it = 0; it < 4; ++it) {
      int idx = it * 256 + t;
      bf16x8 v = *(const bf16x8*)(Kp + (size_t)(kt * 128 + (idx >> 3)) * 64 + (idx & 7) * 8);
      *(bf16x8*)(Ks + (idx >> 3) * 72 + (idx & 7) * 8) = v;
    }
    __syncthreads();
    f32x4 st[8][2] = {};
#pragma unroll
    for (int df = 0; df < 2; ++df) {
      bf16x8 kf[8];
#pragma unroll
      for (int ni = 0; ni < 8; ni++)
        kf[ni] = *(const bf16x8*)(Ks + (ni * 16 + r) * 72 + df * 32 + g * 8);
#pragma unroll
      for (int ni = 0; ni < 8; ni++)
#pragma unroll
        for (int qj = 0; qj < 2; qj++) st[ni][qj] = mfma16(kf[ni], qf[qj][df], st[ni][qj]);
    }
#pragma unroll
    for (int qj = 0; qj < 2; qj++) {
      float vmax = -1e30f;
#pragma unroll
      for (int ni = 0; ni < 8; ni++)
#pragma unroll
        for (int q4 = 0; q4 < 4; q4++) vmax = fmaxf(vmax, st[ni][qj][q4]);
      vmax = fmaxf(vmax, __shfl_xor(vmax, 16));
      vmax = fmaxf(vmax, __shfl_xor(vmax, 32));
      float mnew = fmaxf(mrow[qj], vmax);
      float ssum = 0.f;
#pragma unroll
      for (int ni = 0; ni < 8; ni++)
#pragma unroll
        for (int q4 = 0; q4 < 4; q4++)
          ssum += exp2f((st[ni][qj][q4] - mnew) * 1.44269504f);
      ssum += __shfl_xor(ssum, 16);
      ssum += __shfl_xor(ssum, 32);
      lrow[qj] = lrow[qj] * exp2f((mrow[qj] - mnew) * 1.44269504f) + ssum;
      mrow[qj] = mnew;
    }
    __syncthreads();
  }

#pragma unroll
  for (int qj = 0; qj < 2; qj++) {
    float inv = 1.0f / lrow[qj];
    if (g == 0) rls[w * 32 + qj * 16 + r] = inv;
  }

  // -------- pass B: probs + PV with final m,l --------
  f32x4 cacc[2][4] = {};
  for (int kt = 0; kt < 16; ++kt) {
#pragma unroll
    for (int it = 0; it < 4; ++it) {
      int idx = it * 256 + t;
      bf16x8 v = *(const bf16x8*)(Kp + (size_t)(kt * 128 + (idx >> 3)) * 64 + (idx & 7) * 8);
      *(bf16x8*)(Ks + (idx >> 3) * 72 + (idx & 7) * 8) = v;
    }
    // V tile transposed into Vt[d][k] (reg-staged pairs)
#pragma unroll
    for (int it = 0; it < 2; ++it) {
      int idx = it * 256 + t;
      int kp = (idx >> 3) * 2, d0 = (idx & 7) * 8;
      bf16x8 v0 = *(const bf16x8*)(Vp + (size_t)(kt * 128 + kp) * 64 + d0);
      bf16x8 v1 = *(const bf16x8*)(Vp + (size_t)(kt * 128 + kp + 1) * 64 + d0);
#pragma unroll
      for (int e = 0; e < 8; e++) {
        unsigned int pk = (unsigned int)(unsigned short)v0[e] |
                          ((unsigned int)(unsigned short)v1[e] << 16);
        *(unsigned int*)(Vt + (d0 + e) * 136 + kp) = pk;
      }
    }
    __syncthreads();
    // QK^T (swapped)
    f32x4 st[8][2] = {};
#pragma unroll
    for (int df = 0; df < 2; ++df) {
      bf16x8 kf[8];
#pragma unroll
      for (int ni = 0; ni < 8; ni++)
        kf[ni] = *(const bf16x8*)(Ks + (ni * 16 + r) * 72 + df * 32 + g * 8);
#pragma unroll
      for (int ni = 0; ni < 8; ni++)
#pragma unroll
        for (int qj = 0; qj < 2; qj++) st[ni][qj] = mfma16(kf[ni], qf[qj][df], st[ni][qj]);
    }
    // P = exp(s - m) -> bf16, packed 4-consecutive-k writes into Ps[w][q][k]
#pragma unroll
    for (int ni = 0; ni < 8; ni++)
#pragma unroll
      for (int qj = 0; qj < 2; qj++) {
        bf16x4v pk;
#pragma unroll
        for (int q4 = 0; q4 < 4; q4++)
          pk[q4] = f2bs(exp2f((st[ni][qj][q4] - mrow[qj]) * 1.44269504f));
        *(bf16x4v*)(&Ps[w][(qj * 16 + r) * 136 + ni * 16 + g * 4]) = pk;
      }
    // PV: A = P (row=q), B = V^T (col=dv)
#pragma unroll
    for (int kf4 = 0; kf4 < 4; ++kf4) {
      bf16x8 pa[2], vb[4];
#pragma unroll
      for (int qj = 0; qj < 2; qj++)
        pa[qj] = *(const bf16x8*)(&Ps[w][(qj * 16 + r) * 136 + kf4 * 32 + g * 8]);
#pragma unroll
      for (int nj = 0; nj < 4; nj++)
        vb[nj] = *(const bf16x8*)(Vt + (nj * 16 + r) * 136 + kf4 * 32 + g * 8);
#pragma unroll
      for (int qj = 0; qj < 2; qj++)
#pragma unroll
        for (int nj = 0; nj < 4; nj++) cacc[qj][nj] = mfma16(pa[qj], vb[nj], cacc[qj][nj]);
    }
    // probs write (coalesced: 16 lanes x 32B per row segment), normalized by 1/l
#pragma unroll
    for (int rr = 0; rr < 8; ++rr) {
      int qt = w * 32 + rr * 4 + g;
      bf16x8 pv = *(const bf16x8*)(&Ps[w][(rr * 4 + g) * 136 + r * 8]);
      float scl = rls[qt];
      float4 oA, oB;
      oA.x = bs2f(pv[0]) * scl; oA.y = bs2f(pv[1]) * scl;
      oA.z = bs2f(pv[2]) * scl; oA.w = bs2f(pv[3]) * scl;
      oB.x = bs2f(pv[4]) * scl; oB.y = bs2f(pv[5]) * scl;
      oB.z = bs2f(pv[6]) * scl; oB.w = bs2f(pv[7]) * scl;
      float* dst = Pp + (size_t)(q0 + qt) * 2048 + kt * 128 + r * 8;
      *(float4*)dst = oA;
      *((float4*)dst + 1) = oB;
    }
    __syncthreads();
  }
  // ctx epilogue: normalize and store bf16 [B,S,E]
#pragma unroll
  for (int qj = 0; qj < 2; qj++)
#pragma unroll
    for (int nj = 0; nj < 4; nj++)
#pragma unroll
      for (int q4 = 0; q4 < 4; q4++) {
        int qt = w * 32 + qj * 16 + g * 4 + q4;
        float val = cacc[qj][nj][q4] * rls[qt];
        ctx[((size_t)(bb * 2048 + q0 + qt)) * 1024 + hh * 64 + nj * 16 + r] = f2bs(val);
      }
}

extern "C" void kernel_launch(void* const* d_in, const int* in_sizes, int n_in,
                              void* d_out, int out_size, void* d_ws, size_t ws_size,
                              hipStream_t stream) {
  (void)in_sizes; (void)n_in; (void)out_size; (void)ws_size;
  const float* X  = (const float*)d_in[0];
  const float* Wq = (const float*)d_in[1];
  const float* bq = (const float*)d_in[2];
  const float* Wk = (const float*)d_in[3];
  const float* bk = (const float*)d_in[4];
  const float* Wv = (const float*)d_in[5];
  const float* bv = (const float*)d_in[6];
  const float* Wo = (const float*)d_in[7];
  const float* bo = (const float*)d_in[8];
  float* out = (float*)d_out;
  float* probs = out + (size_t)2 * 2048 * 1024;

  short* Xb = (short*)d_ws;                 // 4096x1024
  short* Wt = Xb + (size_t)4194304;         // 4x1024x1024 (q,k,v,o transposed)
  short* Qb = Wt + (size_t)4194304;         // [B,H,S,D]
  short* Kb = Qb + (size_t)4194304;
  short* Vb = Kb + (size_t)4194304;
  short* Cx = Vb + (size_t)4194304;         // ctx [B,S,E]

  cvt_x_kernel<<<2048, 256, 0, stream>>>(X, Xb);
  cvt_wt_kernel<<<dim3(256, 4), 256, 0, stream>>>(Wq, Wk, Wv, Wo, Wt);
  gemm_bt_kernel<0><<<dim3(32, 24), 256, 0, stream>>>(Xb, Wt, bq, bk, bv, Qb, Kb, Vb, nullptr);
  attn_kernel<<<dim3(16, 32), 256, 0, stream>>>(Qb, Kb, Vb, probs, Cx);
  gemm_bt_kernel<1><<<dim3(32, 8), 256, 0, stream>>>(Cx, Wt + (size_t)3 * 1048576, bo,
                                                     nullptr, nullptr, nullptr, nullptr,
                                                     nullptr, out);
}